// Round 1
// baseline (5618.756 us; speedup 1.0000x reference)
//
#include <hip/hip_runtime.h>
#include <hip/hip_bf16.h>
#include <math.h>

#define NEG_SLOPE 0.2f

__device__ __forceinline__ float lrelu(float x) { return x > 0.f ? x : NEG_SLOPE * x; }
__device__ __forceinline__ float dot4(float4 a, float4 b) {
    return a.x * b.x + a.y * b.y + a.z * b.z + a.w * b.w;
}

// ---------------------------------------------------------------------------
// GEMM: Cout[N x 256] = A[N x 128] @ W[128 x 256]
// If aggIn != nullptr: residual epilogue
//   Cout = sig * relu(aggIn) + (1-sig) * (A@W + bres),  sig = sigmoid(gate[0])
// (aggIn may alias Cout; each element read+written by exactly one thread)
// tile 64x64, block 256 threads, 4x4 micro-tile per thread
// ---------------------------------------------------------------------------
__global__ __launch_bounds__(256)
void gemm_k(const float* __restrict__ A, const float* __restrict__ W,
            float* __restrict__ Cout, int Nrows,
            const float* __restrict__ aggIn, const float* __restrict__ bres,
            const float* __restrict__ gate)
{
    __shared__ float As[16][64];   // [k][m]
    __shared__ float Bs[16][64];   // [k][n]
    const int t  = threadIdx.x;
    const int m0 = blockIdx.x * 64;
    const int n0 = blockIdx.y * 64;
    const int tx = t & 15, ty = t >> 4;
    const int lr = t >> 2, lk = (t & 3) * 4;     // A-tile load: row lr, k-offset lk
    const int bk = t >> 4, bn = (t & 15) * 4;    // B-tile load: k-row bk, col bn

    float acc[4][4] = {};

    for (int k0 = 0; k0 < 128; k0 += 16) {
        float4 av = make_float4(0.f, 0.f, 0.f, 0.f);
        const int row = m0 + lr;
        if (row < Nrows)
            av = *reinterpret_cast<const float4*>(A + (size_t)row * 128 + k0 + lk);
        float4 bv = *reinterpret_cast<const float4*>(W + (size_t)(k0 + bk) * 256 + n0 + bn);
        __syncthreads();
        As[lk + 0][lr] = av.x; As[lk + 1][lr] = av.y;
        As[lk + 2][lr] = av.z; As[lk + 3][lr] = av.w;
        *reinterpret_cast<float4*>(&Bs[bk][bn]) = bv;
        __syncthreads();
        #pragma unroll
        for (int kk = 0; kk < 16; ++kk) {
            float4 a = *reinterpret_cast<const float4*>(&As[kk][ty * 4]);
            float4 b = *reinterpret_cast<const float4*>(&Bs[kk][tx * 4]);
            float ar[4] = {a.x, a.y, a.z, a.w};
            float br[4] = {b.x, b.y, b.z, b.w};
            #pragma unroll
            for (int i = 0; i < 4; ++i)
                #pragma unroll
                for (int j = 0; j < 4; ++j)
                    acc[i][j] = fmaf(ar[i], br[j], acc[i][j]);
        }
    }

    const bool doRes = (aggIn != nullptr);
    float sig = 0.f, oms = 0.f;
    if (doRes) { sig = 1.f / (1.f + expf(-gate[0])); oms = 1.f - sig; }

    #pragma unroll
    for (int i = 0; i < 4; ++i) {
        const int row = m0 + ty * 4 + i;
        if (row >= Nrows) continue;
        const size_t o = (size_t)row * 256 + n0 + tx * 4;
        float4 c = make_float4(acc[i][0], acc[i][1], acc[i][2], acc[i][3]);
        if (doRes) {
            float4 g = *reinterpret_cast<const float4*>(aggIn + o);
            const float* bb = bres + n0 + tx * 4;
            c.x = sig * fmaxf(g.x, 0.f) + oms * (c.x + bb[0]);
            c.y = sig * fmaxf(g.y, 0.f) + oms * (c.y + bb[1]);
            c.z = sig * fmaxf(g.z, 0.f) + oms * (c.z + bb[2]);
            c.w = sig * fmaxf(g.w, 0.f) + oms * (c.w + bb[3]);
        }
        *reinterpret_cast<float4*>(Cout + o) = c;
    }
}

// ---------------------------------------------------------------------------
// Per-pool head scores: el[n,k] = sum_d pool[n,k,d]*wvA[k*64+d]
//                       er[n,k] = sum_d pool[n,k,d]*wvB[k*64+32+d]
// one wave per node, lane covers 4 dims of head k=lane>>3
// ---------------------------------------------------------------------------
__global__ __launch_bounds__(256)
void scores_k(const float* __restrict__ pool,
              const float* __restrict__ wvA, const float* __restrict__ wvB,
              float* __restrict__ elOut, float* __restrict__ erOut, int Nrows)
{
    const int lane = threadIdx.x & 63;
    const int n = blockIdx.x * 4 + (threadIdx.x >> 6);
    if (n >= Nrows) return;
    const int k = lane >> 3, d0 = (lane & 7) * 4;
    float4 f  = *reinterpret_cast<const float4*>(pool + (size_t)n * 256 + lane * 4);
    float4 wl = *reinterpret_cast<const float4*>(wvA + k * 64 + d0);
    float4 wr = *reinterpret_cast<const float4*>(wvB + k * 64 + 32 + d0);
    float pl = dot4(f, wl);
    float pr = dot4(f, wr);
    #pragma unroll
    for (int m = 1; m < 8; m <<= 1) {
        pl += __shfl_xor(pl, m, 64);
        pr += __shfl_xor(pr, m, 64);
    }
    if ((lane & 7) == 0) {
        elOut[(size_t)n * 8 + k] = pl;
        erOut[(size_t)n * 8 + k] = pr;
    }
}

// ---------------------------------------------------------------------------
// Edge pass 1: ex[e,k] = exp(lrelu(el[src]+er[dst])); s[dst,k] += ex
// (max-subtraction skipped: |e| <= ~10 so exp is safe in fp32; softmax is
//  shift-invariant so result is mathematically identical)
// ---------------------------------------------------------------------------
__global__ __launch_bounds__(256)
void epass1_k(const int* __restrict__ src, const int* __restrict__ dst,
              const float* __restrict__ el, const float* __restrict__ er,
              float* __restrict__ ex, float* __restrict__ s, int E)
{
    const int e = blockIdx.x * 256 + threadIdx.x;
    if (e >= E) return;
    const int si = src[e], di = dst[e];
    float4 l0 = *reinterpret_cast<const float4*>(el + (size_t)si * 8);
    float4 l1 = *reinterpret_cast<const float4*>(el + (size_t)si * 8 + 4);
    float4 r0 = *reinterpret_cast<const float4*>(er + (size_t)di * 8);
    float4 r1 = *reinterpret_cast<const float4*>(er + (size_t)di * 8 + 4);
    float v[8] = { l0.x + r0.x, l0.y + r0.y, l0.z + r0.z, l0.w + r0.w,
                   l1.x + r1.x, l1.y + r1.y, l1.z + r1.z, l1.w + r1.w };
    #pragma unroll
    for (int k = 0; k < 8; ++k) v[k] = expf(lrelu(v[k]));
    *reinterpret_cast<float4*>(ex + (size_t)e * 8)     = make_float4(v[0], v[1], v[2], v[3]);
    *reinterpret_cast<float4*>(ex + (size_t)e * 8 + 4) = make_float4(v[4], v[5], v[6], v[7]);
    #pragma unroll
    for (int k = 0; k < 8; ++k) atomicAdd(s + (size_t)di * 8 + k, v[k]);
}

// ---------------------------------------------------------------------------
// Edge pass 2: agg[dst] += fs[src] * (ex[e]/s[dst])  — one wave per edge
// ---------------------------------------------------------------------------
__global__ __launch_bounds__(256)
void epass2_k(const int* __restrict__ src, const int* __restrict__ dst,
              const float* __restrict__ fs, const float* __restrict__ ex,
              const float* __restrict__ s, float* __restrict__ agg, int E)
{
    const int lane = threadIdx.x & 63;
    const int e = blockIdx.x * 4 + (threadIdx.x >> 6);
    if (e >= E) return;
    const int si = src[e], di = dst[e];
    const int k = lane >> 3;
    const float a = ex[(size_t)e * 8 + k] / s[(size_t)di * 8 + k];
    float4 f = *reinterpret_cast<const float4*>(fs + (size_t)si * 256 + lane * 4);
    float* o = agg + (size_t)di * 256 + lane * 4;
    atomicAdd(o + 0, f.x * a);
    atomicAdd(o + 1, f.y * a);
    atomicAdd(o + 2, f.z * a);
    atomicAdd(o + 3, f.w * a);
}

// ---------------------------------------------------------------------------
// Combine: cross-relation softmax fusion over h = [h_ui, h_ii, h_iir]
// (inputs here are already post-residual). out_iu = h_iu passthrough.
// one wave per node
// ---------------------------------------------------------------------------
__global__ __launch_bounds__(256)
void combine_k(const float* __restrict__ hui, const float* __restrict__ hiu,
               const float* __restrict__ hii, const float* __restrict__ hiir,
               const float* __restrict__ attn_ui, const float* __restrict__ attn_ii,
               const float* __restrict__ attn_iir,
               float* __restrict__ out, int Nrows)
{
    const int lane = threadIdx.x & 63;
    const int n = blockIdx.x * 4 + (threadIdx.x >> 6);
    if (n >= Nrows) return;
    const size_t o = (size_t)n * 256 + lane * 4;
    float4 f0  = *reinterpret_cast<const float4*>(hui  + o);
    float4 f1  = *reinterpret_cast<const float4*>(hii  + o);
    float4 f2  = *reinterpret_cast<const float4*>(hiir + o);
    float4 fiu = *reinterpret_cast<const float4*>(hiu  + o);
    float4 w0 = *reinterpret_cast<const float4*>(attn_ui  + lane * 4);
    float4 w1 = *reinterpret_cast<const float4*>(attn_ii  + lane * 4);
    float4 w2 = *reinterpret_cast<const float4*>(attn_iir + lane * 4);

    float p[3][3];   // [which attn vec X][relation r]
    p[0][0] = dot4(w0, f0); p[0][1] = dot4(w0, f1); p[0][2] = dot4(w0, f2);
    p[1][0] = dot4(w1, f0); p[1][1] = dot4(w1, f1); p[1][2] = dot4(w1, f2);
    p[2][0] = dot4(w2, f0); p[2][1] = dot4(w2, f1); p[2][2] = dot4(w2, f2);
    #pragma unroll
    for (int x = 0; x < 3; ++x)
        #pragma unroll
        for (int r = 0; r < 3; ++r)
            #pragma unroll
            for (int m = 1; m < 8; m <<= 1)
                p[x][r] += __shfl_xor(p[x][r], m, 64);

    const size_t NK = (size_t)Nrows * 256;
    // X: 0 -> out_ui (offset 0), 1 -> out_ii (2*NK), 2 -> out_iir (3*NK)
    const size_t xoff[3] = {0, 2 * NK, 3 * NK};
    #pragma unroll
    for (int x = 0; x < 3; ++x) {
        float a0 = lrelu(p[x][0]), a1 = lrelu(p[x][1]), a2 = lrelu(p[x][2]);
        float mx = fmaxf(a0, fmaxf(a1, a2));
        float e0 = expf(a0 - mx), e1 = expf(a1 - mx), e2 = expf(a2 - mx);
        float inv = 1.f / (e0 + e1 + e2);
        e0 *= inv; e1 *= inv; e2 *= inv;
        float4 r;
        r.x = e0 * f0.x + e1 * f1.x + e2 * f2.x;
        r.y = e0 * f0.y + e1 * f1.y + e2 * f2.y;
        r.z = e0 * f0.z + e1 * f1.z + e2 * f2.z;
        r.w = e0 * f0.w + e1 * f1.w + e2 * f2.w;
        *reinterpret_cast<float4*>(out + xoff[x] + o) = r;
    }
    *reinterpret_cast<float4*>(out + NK + o) = fiu;  // out_iu = h_iu
}

// ---------------------------------------------------------------------------
// Relation-level tiny matvecs: wvec[r] = rfeat @ Wrel (512,) and
// ro[r] = rfeat @ Wupd + bupd (256,) written straight to output tail
// ---------------------------------------------------------------------------
struct RelPtrs {
    const float* rf[4];
    const float* Wrel[4];
    const float* Wupd[4];
    const float* bupd[4];
};

__global__ __launch_bounds__(512)
void rel_k(RelPtrs P, float* __restrict__ wvec, float* __restrict__ ro)
{
    const int r = blockIdx.x;
    const int t = threadIdx.x;
    __shared__ float rfs[64];
    if (t < 64) rfs[t] = P.rf[r][t];
    __syncthreads();
    {
        const float* Wc = P.Wrel[r];
        float acc = 0.f;
        #pragma unroll 8
        for (int i = 0; i < 64; ++i) acc = fmaf(rfs[i], Wc[(size_t)i * 512 + t], acc);
        wvec[(size_t)r * 512 + t] = acc;
    }
    if (t < 256) {
        const float* Wc = P.Wupd[r];
        float acc = P.bupd[r][t];
        #pragma unroll 8
        for (int i = 0; i < 64; ++i) acc = fmaf(rfs[i], Wc[(size_t)i * 256 + t], acc);
        ro[(size_t)r * 256 + t] = acc;
    }
}

// ---------------------------------------------------------------------------
extern "C" void kernel_launch(void* const* d_in, const int* in_sizes, int n_in,
                              void* d_out, int out_size, void* d_ws, size_t ws_size,
                              hipStream_t stream)
{
    (void)n_in; (void)out_size; (void)ws_size;
    const float* feat_ui  = (const float*)d_in[0];
    const float* feat_iu  = (const float*)d_in[1];
    const float* feat_ii  = (const float*)d_in[2];
    const float* feat_iir = (const float*)d_in[3];
    const float* W_user   = (const float*)d_in[8];
    const float* W_item   = (const float*)d_in[9];
    const float* Wres_user = (const float*)d_in[18];
    const float* bres_user = (const float*)d_in[19];
    const float* Wres_item = (const float*)d_in[20];
    const float* bres_item = (const float*)d_in[21];
    const float* a_user = (const float*)d_in[22];
    const float* a_item = (const float*)d_in[23];
    const int* srcs[4] = {(const int*)d_in[32], (const int*)d_in[34],
                          (const int*)d_in[36], (const int*)d_in[38]};
    const int* dsts[4] = {(const int*)d_in[33], (const int*)d_in[35],
                          (const int*)d_in[37], (const int*)d_in[39]};
    const int N = in_sizes[0] / 128;
    const int Es[4] = {in_sizes[32], in_sizes[34], in_sizes[36], in_sizes[38]};

    float* ws = (float*)d_ws;
    const size_t NP = (size_t)N * 256;
    const size_t N8 = (size_t)N * 8;

    // pools: P0 = feat_iu@W_user, P1 = feat_ui@W_item,
    //        P2 = feat_ii_rev@W_item, P3 = feat_ii@W_item
    float* P[4];
    for (int r = 0; r < 4; ++r) P[r] = ws + (size_t)r * NP;
    float* agg[4];
    for (int r = 0; r < 4; ++r) agg[r] = ws + (size_t)(4 + r) * NP;
    float* scb = ws + 8 * NP;
    float *el[4], *er[4];
    for (int r = 0; r < 4; ++r) { el[r] = scb + (size_t)(2 * r) * N8; er[r] = scb + (size_t)(2 * r + 1) * N8; }
    float* sb = scb + 8 * N8;
    float* sArr[4];
    for (int r = 0; r < 4; ++r) sArr[r] = sb + (size_t)r * N8;
    float* exb = sb + 4 * N8;
    float* exArr[4];
    {
        size_t off = 0;
        for (int r = 0; r < 4; ++r) { exArr[r] = exb + off; off += (size_t)Es[r] * 8; }
    }
    float* wvec = exArr[3] + (size_t)Es[3] * 8;   // 4 x 512
    float* out = (float*)d_out;

    // zero the accumulators (agg 4*NP, s 4*N8)
    hipMemsetAsync(ws + 4 * NP, 0, 4 * NP * sizeof(float), stream);
    hipMemsetAsync(sb, 0, 4 * N8 * sizeof(float), stream);

    // relation matvecs (wvec to ws, ro straight to output tail)
    RelPtrs rp;
    rp.rf[0]   = (const float*)d_in[4];  rp.rf[1]   = (const float*)d_in[5];
    rp.rf[2]   = (const float*)d_in[6];  rp.rf[3]   = (const float*)d_in[7];
    rp.Wrel[0] = (const float*)d_in[10]; rp.Wrel[1] = (const float*)d_in[11];
    rp.Wrel[2] = (const float*)d_in[12]; rp.Wrel[3] = (const float*)d_in[13];
    rp.Wupd[0] = (const float*)d_in[24]; rp.Wupd[1] = (const float*)d_in[26];
    rp.Wupd[2] = (const float*)d_in[28]; rp.Wupd[3] = (const float*)d_in[30];
    rp.bupd[0] = (const float*)d_in[25]; rp.bupd[1] = (const float*)d_in[27];
    rp.bupd[2] = (const float*)d_in[29]; rp.bupd[3] = (const float*)d_in[31];
    rel_k<<<dim3(4), dim3(512), 0, stream>>>(rp, wvec, out + 4 * NP);

    // attention pools
    dim3 gg((N + 63) / 64, 4);
    gemm_k<<<gg, 256, 0, stream>>>(feat_iu,  W_user, P[0], N, nullptr, nullptr, nullptr);
    gemm_k<<<gg, 256, 0, stream>>>(feat_ui,  W_item, P[1], N, nullptr, nullptr, nullptr);
    gemm_k<<<gg, 256, 0, stream>>>(feat_iir, W_item, P[2], N, nullptr, nullptr, nullptr);
    gemm_k<<<gg, 256, 0, stream>>>(feat_ii,  W_item, P[3], N, nullptr, nullptr, nullptr);

    // head scores: pool -> (el of its fs-relation, er of its fd-relation)
    const int nb4 = (N + 3) / 4;
    scores_k<<<nb4, 256, 0, stream>>>(P[0], wvec + 0 * 512, wvec + 1 * 512, el[0], er[1], N);
    scores_k<<<nb4, 256, 0, stream>>>(P[1], wvec + 1 * 512, wvec + 0 * 512, el[1], er[0], N);
    scores_k<<<nb4, 256, 0, stream>>>(P[2], wvec + 2 * 512, wvec + 3 * 512, el[2], er[3], N);
    scores_k<<<nb4, 256, 0, stream>>>(P[3], wvec + 3 * 512, wvec + 2 * 512, el[3], er[2], N);

    // edge softmax passes
    for (int r = 0; r < 4; ++r)
        epass1_k<<<(Es[r] + 255) / 256, 256, 0, stream>>>(srcs[r], dsts[r], el[r], er[r],
                                                          exArr[r], sArr[r], Es[r]);
    for (int r = 0; r < 4; ++r)
        epass2_k<<<(Es[r] + 3) / 4, 256, 0, stream>>>(srcs[r], dsts[r], P[r],
                                                      exArr[r], sArr[r], agg[r], Es[r]);

    // gated residual (fused GEMM epilogue, in-place on agg)
    gemm_k<<<gg, 256, 0, stream>>>(feat_ui,  Wres_item, agg[0], N, agg[0], bres_item, a_item);
    gemm_k<<<gg, 256, 0, stream>>>(feat_iu,  Wres_user, agg[1], N, agg[1], bres_user, a_user);
    gemm_k<<<gg, 256, 0, stream>>>(feat_ii,  Wres_item, agg[2], N, agg[2], bres_item, a_item);
    gemm_k<<<gg, 256, 0, stream>>>(feat_iir, Wres_item, agg[3], N, agg[3], bres_item, a_item);

    // cross-relation fusion + passthrough + outputs
    combine_k<<<nb4, 256, 0, stream>>>(agg[0], agg[1], agg[2], agg[3],
                                       (const float*)d_in[14], (const float*)d_in[16],
                                       (const float*)d_in[17], out, N);
}

// Round 2
// 1536.612 us; speedup vs baseline: 3.6566x; 3.6566x over previous
//
#include <hip/hip_runtime.h>
#include <hip/hip_bf16.h>
#include <math.h>

#define NEG_SLOPE 0.2f

__device__ __forceinline__ float lrelu(float x) { return x > 0.f ? x : NEG_SLOPE * x; }
__device__ __forceinline__ float dot4(float4 a, float4 b) {
    return a.x * b.x + a.y * b.y + a.z * b.z + a.w * b.w;
}

// ---------------------------------------------------------------------------
// GEMM: Cout[N x 256] = A[N x 128] @ W[128 x 256]
// If aggIn != nullptr: residual epilogue
//   Cout = sig * relu(aggIn) + (1-sig) * (A@W + bres),  sig = sigmoid(gate[0])
// tile 64x64, block 256 threads, 4x4 micro-tile per thread
// ---------------------------------------------------------------------------
__global__ __launch_bounds__(256)
void gemm_k(const float* __restrict__ A, const float* __restrict__ W,
            float* __restrict__ Cout, int Nrows,
            const float* __restrict__ aggIn, const float* __restrict__ bres,
            const float* __restrict__ gate)
{
    __shared__ float As[16][64];   // [k][m]
    __shared__ float Bs[16][64];   // [k][n]
    const int t  = threadIdx.x;
    const int m0 = blockIdx.x * 64;
    const int n0 = blockIdx.y * 64;
    const int tx = t & 15, ty = t >> 4;
    const int lr = t >> 2, lk = (t & 3) * 4;
    const int bk = t >> 4, bn = (t & 15) * 4;

    float acc[4][4] = {};

    for (int k0 = 0; k0 < 128; k0 += 16) {
        float4 av = make_float4(0.f, 0.f, 0.f, 0.f);
        const int row = m0 + lr;
        if (row < Nrows)
            av = *reinterpret_cast<const float4*>(A + (size_t)row * 128 + k0 + lk);
        float4 bv = *reinterpret_cast<const float4*>(W + (size_t)(k0 + bk) * 256 + n0 + bn);
        __syncthreads();
        As[lk + 0][lr] = av.x; As[lk + 1][lr] = av.y;
        As[lk + 2][lr] = av.z; As[lk + 3][lr] = av.w;
        *reinterpret_cast<float4*>(&Bs[bk][bn]) = bv;
        __syncthreads();
        #pragma unroll
        for (int kk = 0; kk < 16; ++kk) {
            float4 a = *reinterpret_cast<const float4*>(&As[kk][ty * 4]);
            float4 b = *reinterpret_cast<const float4*>(&Bs[kk][tx * 4]);
            float ar[4] = {a.x, a.y, a.z, a.w};
            float br[4] = {b.x, b.y, b.z, b.w};
            #pragma unroll
            for (int i = 0; i < 4; ++i)
                #pragma unroll
                for (int j = 0; j < 4; ++j)
                    acc[i][j] = fmaf(ar[i], br[j], acc[i][j]);
        }
    }

    const bool doRes = (aggIn != nullptr);
    float sig = 0.f, oms = 0.f;
    if (doRes) { sig = 1.f / (1.f + expf(-gate[0])); oms = 1.f - sig; }

    #pragma unroll
    for (int i = 0; i < 4; ++i) {
        const int row = m0 + ty * 4 + i;
        if (row >= Nrows) continue;
        const size_t o = (size_t)row * 256 + n0 + tx * 4;
        float4 c = make_float4(acc[i][0], acc[i][1], acc[i][2], acc[i][3]);
        if (doRes) {
            float4 g = *reinterpret_cast<const float4*>(aggIn + o);
            const float* bb = bres + n0 + tx * 4;
            c.x = sig * fmaxf(g.x, 0.f) + oms * (c.x + bb[0]);
            c.y = sig * fmaxf(g.y, 0.f) + oms * (c.y + bb[1]);
            c.z = sig * fmaxf(g.z, 0.f) + oms * (c.z + bb[2]);
            c.w = sig * fmaxf(g.w, 0.f) + oms * (c.w + bb[3]);
        }
        *reinterpret_cast<float4*>(Cout + o) = c;
    }
}

// ---------------------------------------------------------------------------
// Per-pool head scores
// ---------------------------------------------------------------------------
__global__ __launch_bounds__(256)
void scores_k(const float* __restrict__ pool,
              const float* __restrict__ wvA, const float* __restrict__ wvB,
              float* __restrict__ elOut, float* __restrict__ erOut, int Nrows)
{
    const int lane = threadIdx.x & 63;
    const int n = blockIdx.x * 4 + (threadIdx.x >> 6);
    if (n >= Nrows) return;
    const int k = lane >> 3, d0 = (lane & 7) * 4;
    float4 f  = *reinterpret_cast<const float4*>(pool + (size_t)n * 256 + lane * 4);
    float4 wl = *reinterpret_cast<const float4*>(wvA + k * 64 + d0);
    float4 wr = *reinterpret_cast<const float4*>(wvB + k * 64 + 32 + d0);
    float pl = dot4(f, wl);
    float pr = dot4(f, wr);
    #pragma unroll
    for (int m = 1; m < 8; m <<= 1) {
        pl += __shfl_xor(pl, m, 64);
        pr += __shfl_xor(pr, m, 64);
    }
    if ((lane & 7) == 0) {
        elOut[(size_t)n * 8 + k] = pl;
        erOut[(size_t)n * 8 + k] = pr;
    }
}

// ---------------------------------------------------------------------------
// CSR build (batched over 4 relations via blockIdx.y)
// ---------------------------------------------------------------------------
struct EdgePtrs {
    const int* src[4];
    const int* dst[4];
    int E[4];
    int csrOff[4];
};

__global__ __launch_bounds__(256)
void hist_k(EdgePtrs ep, int* __restrict__ counts4, int N)
{
    const int r = blockIdx.y;
    const int e = blockIdx.x * 256 + threadIdx.x;
    if (e < ep.E[r]) atomicAdd(counts4 + (size_t)r * N + ep.dst[r][e], 1);
}

// per-block (1024 elems) sums
__global__ __launch_bounds__(256)
void blksum_k(const int* __restrict__ counts4, int* __restrict__ blksum4, int N)
{
    const int r = blockIdx.y;
    const int* c = counts4 + (size_t)r * N;
    const int base = blockIdx.x * 1024 + threadIdx.x;
    int s = 0;
    #pragma unroll
    for (int i = 0; i < 4; ++i) { int idx = base + i * 256; if (idx < N) s += c[idx]; }
    __shared__ int sd[256];
    sd[threadIdx.x] = s; __syncthreads();
    for (int off = 128; off > 0; off >>= 1) {
        if (threadIdx.x < off) sd[threadIdx.x] += sd[threadIdx.x + off];
        __syncthreads();
    }
    if (threadIdx.x == 0) blksum4[r * 1024 + blockIdx.x] = sd[0];
}

// single-block exclusive scan of per-block sums (in place); nbx <= 1024
__global__ __launch_bounds__(1024)
void scanblk_k(int* __restrict__ blksum4, int nbx)
{
    const int r = blockIdx.x;
    const int t = threadIdx.x;
    __shared__ int sd[1024];
    int v = (t < nbx) ? blksum4[r * 1024 + t] : 0;
    sd[t] = v; __syncthreads();
    for (int off = 1; off < 1024; off <<= 1) {
        int u = (t >= off) ? sd[t - off] : 0;
        __syncthreads();
        sd[t] += u;
        __syncthreads();
    }
    if (t < nbx) blksum4[r * 1024 + t] = sd[t] - v;   // exclusive
}

// per-element exclusive scan -> cursor (= row start, later mutated to row end)
__global__ __launch_bounds__(256)
void cursor_k(const int* __restrict__ counts4, const int* __restrict__ blkoff4,
              int* __restrict__ cursor4, int N)
{
    const int r = blockIdx.y;
    const int* c = counts4 + (size_t)r * N;
    int* cur = cursor4 + (size_t)r * N;
    const int t = threadIdx.x;
    const int base = blockIdx.x * 1024 + t * 4;
    const int c0 = (base + 0 < N) ? c[base + 0] : 0;
    const int c1 = (base + 1 < N) ? c[base + 1] : 0;
    const int c2 = (base + 2 < N) ? c[base + 2] : 0;
    const int c3 = (base + 3 < N) ? c[base + 3] : 0;
    const int tsum = c0 + c1 + c2 + c3;
    __shared__ int sd[256];
    sd[t] = tsum; __syncthreads();
    for (int off = 1; off < 256; off <<= 1) {
        int u = (t >= off) ? sd[t - off] : 0;
        __syncthreads();
        sd[t] += u;
        __syncthreads();
    }
    int excl = sd[t] - tsum + blkoff4[r * 1024 + blockIdx.x];
    if (base + 0 < N) cur[base + 0] = excl;
    if (base + 1 < N) cur[base + 1] = excl + c0;
    if (base + 2 < N) cur[base + 2] = excl + c0 + c1;
    if (base + 3 < N) cur[base + 3] = excl + c0 + c1 + c2;
}

// scatter: store SRC node index into dst-sorted order; cursor -> row end
__global__ __launch_bounds__(256)
void scatter_k(EdgePtrs ep, int* __restrict__ cursor4, int* __restrict__ csr_src, int N)
{
    const int r = blockIdx.y;
    const int e = blockIdx.x * 256 + threadIdx.x;
    if (e < ep.E[r]) {
        const int d = ep.dst[r][e];
        const int pos = atomicAdd(cursor4 + (size_t)r * N + d, 1);
        csr_src[ep.csrOff[r] + pos] = ep.src[r][e];
    }
}

// ---------------------------------------------------------------------------
// Fused edge-softmax + aggregation: one wave per dst node, no atomics.
// agg[n] = (sum_e fs[src_e] * ex_e) / (sum_e ex_e),  ex_e = exp(lrelu(el+er))
// ---------------------------------------------------------------------------
__global__ __launch_bounds__(256)
void aggr_k(const int* __restrict__ csr_src, const int* __restrict__ cursor,
            const int* __restrict__ counts,
            const float* __restrict__ el, const float* __restrict__ er,
            const float* __restrict__ fs, float* __restrict__ agg, int Nrows)
{
    const int lane = threadIdx.x & 63;
    const int n = blockIdx.x * 4 + (threadIdx.x >> 6);
    if (n >= Nrows) return;
    const int k = lane >> 3;
    const int deg = counts[n];
    const int end = cursor[n];           // == start + deg after scatter
    const int start = end - deg;
    const float erk = er[(size_t)n * 8 + k];
    float s = 0.f;
    float4 acc = make_float4(0.f, 0.f, 0.f, 0.f);
    for (int j = start; j < end; ++j) {
        const int si = csr_src[j];
        const float ex = expf(lrelu(el[(size_t)si * 8 + k] + erk));
        s += ex;
        float4 f = *reinterpret_cast<const float4*>(fs + (size_t)si * 256 + lane * 4);
        acc.x = fmaf(f.x, ex, acc.x);
        acc.y = fmaf(f.y, ex, acc.y);
        acc.z = fmaf(f.z, ex, acc.z);
        acc.w = fmaf(f.w, ex, acc.w);
    }
    const float inv = (deg > 0) ? 1.f / s : 0.f;
    float4 o = make_float4(acc.x * inv, acc.y * inv, acc.z * inv, acc.w * inv);
    *reinterpret_cast<float4*>(agg + (size_t)n * 256 + lane * 4) = o;
}

// ---------------------------------------------------------------------------
// Combine: cross-relation softmax fusion; out_iu passthrough
// ---------------------------------------------------------------------------
__global__ __launch_bounds__(256)
void combine_k(const float* __restrict__ hui, const float* __restrict__ hiu,
               const float* __restrict__ hii, const float* __restrict__ hiir,
               const float* __restrict__ attn_ui, const float* __restrict__ attn_ii,
               const float* __restrict__ attn_iir,
               float* __restrict__ out, int Nrows)
{
    const int lane = threadIdx.x & 63;
    const int n = blockIdx.x * 4 + (threadIdx.x >> 6);
    if (n >= Nrows) return;
    const size_t o = (size_t)n * 256 + lane * 4;
    float4 f0  = *reinterpret_cast<const float4*>(hui  + o);
    float4 f1  = *reinterpret_cast<const float4*>(hii  + o);
    float4 f2  = *reinterpret_cast<const float4*>(hiir + o);
    float4 fiu = *reinterpret_cast<const float4*>(hiu  + o);
    float4 w0 = *reinterpret_cast<const float4*>(attn_ui  + lane * 4);
    float4 w1 = *reinterpret_cast<const float4*>(attn_ii  + lane * 4);
    float4 w2 = *reinterpret_cast<const float4*>(attn_iir + lane * 4);

    float p[3][3];
    p[0][0] = dot4(w0, f0); p[0][1] = dot4(w0, f1); p[0][2] = dot4(w0, f2);
    p[1][0] = dot4(w1, f0); p[1][1] = dot4(w1, f1); p[1][2] = dot4(w1, f2);
    p[2][0] = dot4(w2, f0); p[2][1] = dot4(w2, f1); p[2][2] = dot4(w2, f2);
    #pragma unroll
    for (int x = 0; x < 3; ++x)
        #pragma unroll
        for (int r = 0; r < 3; ++r)
            #pragma unroll
            for (int m = 1; m < 8; m <<= 1)
                p[x][r] += __shfl_xor(p[x][r], m, 64);

    const size_t NK = (size_t)Nrows * 256;
    const size_t xoff[3] = {0, 2 * NK, 3 * NK};
    #pragma unroll
    for (int x = 0; x < 3; ++x) {
        float a0 = lrelu(p[x][0]), a1 = lrelu(p[x][1]), a2 = lrelu(p[x][2]);
        float mx = fmaxf(a0, fmaxf(a1, a2));
        float e0 = expf(a0 - mx), e1 = expf(a1 - mx), e2 = expf(a2 - mx);
        float inv = 1.f / (e0 + e1 + e2);
        e0 *= inv; e1 *= inv; e2 *= inv;
        float4 r;
        r.x = e0 * f0.x + e1 * f1.x + e2 * f2.x;
        r.y = e0 * f0.y + e1 * f1.y + e2 * f2.y;
        r.z = e0 * f0.z + e1 * f1.z + e2 * f2.z;
        r.w = e0 * f0.w + e1 * f1.w + e2 * f2.w;
        *reinterpret_cast<float4*>(out + xoff[x] + o) = r;
    }
    *reinterpret_cast<float4*>(out + NK + o) = fiu;
}

// ---------------------------------------------------------------------------
// Relation-level tiny matvecs
// ---------------------------------------------------------------------------
struct RelPtrs {
    const float* rf[4];
    const float* Wrel[4];
    const float* Wupd[4];
    const float* bupd[4];
};

__global__ __launch_bounds__(512)
void rel_k(RelPtrs P, float* __restrict__ wvec, float* __restrict__ ro)
{
    const int r = blockIdx.x;
    const int t = threadIdx.x;
    __shared__ float rfs[64];
    if (t < 64) rfs[t] = P.rf[r][t];
    __syncthreads();
    {
        const float* Wc = P.Wrel[r];
        float acc = 0.f;
        #pragma unroll 8
        for (int i = 0; i < 64; ++i) acc = fmaf(rfs[i], Wc[(size_t)i * 512 + t], acc);
        wvec[(size_t)r * 512 + t] = acc;
    }
    if (t < 256) {
        const float* Wc = P.Wupd[r];
        float acc = P.bupd[r][t];
        #pragma unroll 8
        for (int i = 0; i < 64; ++i) acc = fmaf(rfs[i], Wc[(size_t)i * 256 + t], acc);
        ro[(size_t)r * 256 + t] = acc;
    }
}

// ---------------------------------------------------------------------------
extern "C" void kernel_launch(void* const* d_in, const int* in_sizes, int n_in,
                              void* d_out, int out_size, void* d_ws, size_t ws_size,
                              hipStream_t stream)
{
    (void)n_in; (void)out_size; (void)ws_size;
    const float* feat_ui  = (const float*)d_in[0];
    const float* feat_iu  = (const float*)d_in[1];
    const float* feat_ii  = (const float*)d_in[2];
    const float* feat_iir = (const float*)d_in[3];
    const float* W_user   = (const float*)d_in[8];
    const float* W_item   = (const float*)d_in[9];
    const float* Wres_user = (const float*)d_in[18];
    const float* bres_user = (const float*)d_in[19];
    const float* Wres_item = (const float*)d_in[20];
    const float* bres_item = (const float*)d_in[21];
    const float* a_user = (const float*)d_in[22];
    const float* a_item = (const float*)d_in[23];
    const int N = in_sizes[0] / 128;
    const int Es[4] = {in_sizes[32], in_sizes[34], in_sizes[36], in_sizes[38]};
    int maxE = 0;
    for (int r = 0; r < 4; ++r) maxE = Es[r] > maxE ? Es[r] : maxE;

    float* ws = (float*)d_ws;
    const size_t NP = (size_t)N * 256;
    const size_t N8 = (size_t)N * 8;

    float* P[4];
    for (int r = 0; r < 4; ++r) P[r] = ws + (size_t)r * NP;
    float* agg[4];
    for (int r = 0; r < 4; ++r) agg[r] = ws + (size_t)(4 + r) * NP;
    float* scb = ws + 8 * NP;
    float *el[4], *er[4];
    for (int r = 0; r < 4; ++r) { el[r] = scb + (size_t)(2 * r) * N8; er[r] = scb + (size_t)(2 * r + 1) * N8; }
    float* wvec = scb + 8 * N8;                       // 4 x 512
    // int region
    int* ib = (int*)(wvec + 4 * 512);
    int* counts4 = ib;                                 // 4*N
    int* cursor4 = counts4 + 4 * (size_t)N;            // 4*N
    int* blksum4 = cursor4 + 4 * (size_t)N;            // 4*1024
    int* csr_src = blksum4 + 4 * 1024;                 // sum Es
    float* out = (float*)d_out;

    EdgePtrs ep;
    {
        int off = 0;
        const int si[4] = {32, 34, 36, 38};
        for (int r = 0; r < 4; ++r) {
            ep.src[r] = (const int*)d_in[si[r]];
            ep.dst[r] = (const int*)d_in[si[r] + 1];
            ep.E[r] = Es[r];
            ep.csrOff[r] = off;
            off += Es[r];
        }
    }

    // zero histogram counters
    hipMemsetAsync(counts4, 0, 4 * (size_t)N * sizeof(int), stream);

    // relation matvecs (wvec to ws, ro straight to output tail)
    RelPtrs rp;
    rp.rf[0]   = (const float*)d_in[4];  rp.rf[1]   = (const float*)d_in[5];
    rp.rf[2]   = (const float*)d_in[6];  rp.rf[3]   = (const float*)d_in[7];
    rp.Wrel[0] = (const float*)d_in[10]; rp.Wrel[1] = (const float*)d_in[11];
    rp.Wrel[2] = (const float*)d_in[12]; rp.Wrel[3] = (const float*)d_in[13];
    rp.Wupd[0] = (const float*)d_in[24]; rp.Wupd[1] = (const float*)d_in[26];
    rp.Wupd[2] = (const float*)d_in[28]; rp.Wupd[3] = (const float*)d_in[30];
    rp.bupd[0] = (const float*)d_in[25]; rp.bupd[1] = (const float*)d_in[27];
    rp.bupd[2] = (const float*)d_in[29]; rp.bupd[3] = (const float*)d_in[31];
    rel_k<<<dim3(4), dim3(512), 0, stream>>>(rp, wvec, out + 4 * NP);

    // CSR build (batched over relations)
    const int geb = (maxE + 255) / 256;
    const int nbx = (N + 1023) / 1024;
    hist_k<<<dim3(geb, 4), 256, 0, stream>>>(ep, counts4, N);
    blksum_k<<<dim3(nbx, 4), 256, 0, stream>>>(counts4, blksum4, N);
    scanblk_k<<<dim3(4), 1024, 0, stream>>>(blksum4, nbx);
    cursor_k<<<dim3(nbx, 4), 256, 0, stream>>>(counts4, blksum4, cursor4, N);
    scatter_k<<<dim3(geb, 4), 256, 0, stream>>>(ep, cursor4, csr_src, N);

    // attention pools
    dim3 gg((N + 63) / 64, 4);
    gemm_k<<<gg, 256, 0, stream>>>(feat_iu,  W_user, P[0], N, nullptr, nullptr, nullptr);
    gemm_k<<<gg, 256, 0, stream>>>(feat_ui,  W_item, P[1], N, nullptr, nullptr, nullptr);
    gemm_k<<<gg, 256, 0, stream>>>(feat_iir, W_item, P[2], N, nullptr, nullptr, nullptr);
    gemm_k<<<gg, 256, 0, stream>>>(feat_ii,  W_item, P[3], N, nullptr, nullptr, nullptr);

    // head scores
    const int nb4 = (N + 3) / 4;
    scores_k<<<nb4, 256, 0, stream>>>(P[0], wvec + 0 * 512, wvec + 1 * 512, el[0], er[1], N);
    scores_k<<<nb4, 256, 0, stream>>>(P[1], wvec + 1 * 512, wvec + 0 * 512, el[1], er[0], N);
    scores_k<<<nb4, 256, 0, stream>>>(P[2], wvec + 2 * 512, wvec + 3 * 512, el[2], er[3], N);
    scores_k<<<nb4, 256, 0, stream>>>(P[3], wvec + 3 * 512, wvec + 2 * 512, el[3], er[2], N);

    // fused softmax + aggregation, one relation at a time (keeps fs pool L3-hot)
    for (int r = 0; r < 4; ++r)
        aggr_k<<<nb4, 256, 0, stream>>>(csr_src + ep.csrOff[r],
                                        cursor4 + (size_t)r * N,
                                        counts4 + (size_t)r * N,
                                        el[r], er[r], P[r], agg[r], N);

    // gated residual (fused GEMM epilogue, in-place on agg)
    gemm_k<<<gg, 256, 0, stream>>>(feat_ui,  Wres_item, agg[0], N, agg[0], bres_item, a_item);
    gemm_k<<<gg, 256, 0, stream>>>(feat_iu,  Wres_user, agg[1], N, agg[1], bres_user, a_user);
    gemm_k<<<gg, 256, 0, stream>>>(feat_ii,  Wres_item, agg[2], N, agg[2], bres_item, a_item);
    gemm_k<<<gg, 256, 0, stream>>>(feat_iir, Wres_item, agg[3], N, agg[3], bres_item, a_item);

    // cross-relation fusion + passthrough + outputs
    combine_k<<<nb4, 256, 0, stream>>>(agg[0], agg[1], agg[2], agg[3],
                                       (const float*)d_in[14], (const float*)d_in[16],
                                       (const float*)d_in[17], out, N);
}

// Round 4
// 1093.913 us; speedup vs baseline: 5.1364x; 1.4047x over previous
//
#include <hip/hip_runtime.h>
#include <hip/hip_bf16.h>
#include <math.h>

#define NEG_SLOPE 0.2f

using bf16x8 = __attribute__((ext_vector_type(8))) short;
using f32x4  = __attribute__((ext_vector_type(4))) float;
using u16x8  = __attribute__((ext_vector_type(8))) unsigned short;
using u16x4  = __attribute__((ext_vector_type(4))) unsigned short;

__device__ __forceinline__ float lrelu(float x) { return x > 0.f ? x : NEG_SLOPE * x; }
__device__ __forceinline__ float dot4(float4 a, float4 b) {
    return a.x * b.x + a.y * b.y + a.z * b.z + a.w * b.w;
}
__device__ __forceinline__ unsigned short f2b(float x) {
    union { float f; unsigned u; } v; v.f = x;
    unsigned r = v.u + 0x7fff + ((v.u >> 16) & 1);
    return (unsigned short)(r >> 16);
}
__device__ __forceinline__ float b2f(unsigned short b) {
    union { unsigned u; float f; } v; v.u = ((unsigned)b) << 16;
    return v.f;
}
__device__ __forceinline__ float4 load4b(const unsigned short* p) {
    u16x4 u = *reinterpret_cast<const u16x4*>(p);
    return make_float4(b2f(u[0]), b2f(u[1]), b2f(u[2]), b2f(u[3]));
}

// ---------------------------------------------------------------------------
// Pack Wcat = [W1 | W2] (each 128x256 fp32, k-major) into MFMA B-fragment
// linear order, bf16:  Bp[((nb*4+ks)*64+lane)*8 + e] = Wcat[k][n]
//   n = nb*16 + (lane&15),  k = ks*32 + (lane>>4)*8 + e
// ---------------------------------------------------------------------------
__global__ __launch_bounds__(256)
void pack_b_k(const float* __restrict__ W1, const float* __restrict__ W2,
              unsigned short* __restrict__ Bp)
{
    const int gid = blockIdx.x * 256 + threadIdx.x;  // 0..8191
    const int lane = gid & 63;
    const int grp = gid >> 6;          // 0..127
    const int ks = grp & 3;
    const int nb = grp >> 2;           // 0..31
    const int n = nb * 16 + (lane & 15);
    const int k0 = ks * 32 + (lane >> 4) * 8;
    const float* Wsrc = (n < 256) ? (W1 + n) : (W2 + (n - 256));
    u16x8 u;
    #pragma unroll
    for (int e = 0; e < 8; ++e) u[e] = f2b(Wsrc[(size_t)(k0 + e) * 256]);
    *reinterpret_cast<u16x8*>(Bp + (size_t)gid * 8) = u;
}

// ---------------------------------------------------------------------------
// MFMA GEMM: A[N x 128] fp32  @  Wcat[128 x 512] (packed bf16 frags)
//   cols 0..255  -> pool  (bf16)
//   cols 256..511-> resid (bf16) = A@W2 + bres
// block 512 thr (8 waves, 2 row-halves x 4 col-slices), tile 128x512, K=128
// A staged in LDS bf16 with XOR swizzle (row&7)<<4 on the 16B slot.
// ---------------------------------------------------------------------------
__global__ __launch_bounds__(512)
void mfma_gemm_k(const float* __restrict__ A, const unsigned short* __restrict__ Bp,
                 const float* __restrict__ bres,
                 unsigned short* __restrict__ pool, unsigned short* __restrict__ resid,
                 int Nrows)
{
    __shared__ __align__(16) unsigned short Asw[128 * 128];   // 32 KB
    const int t = threadIdx.x;
    const int m0 = blockIdx.x * 128;

    // stage A: 128 rows x 128 k, fp32 -> bf16, swizzled
    #pragma unroll
    for (int i = 0; i < 4; ++i) {
        const int idx = i * 512 + t;        // 0..2047
        const int row = idx >> 4;           // 0..127
        const int cg  = idx & 15;           // 16B chunk (8 bf16)
        float4 a0 = make_float4(0.f, 0.f, 0.f, 0.f), a1 = a0;
        if (m0 + row < Nrows) {
            const float* p = A + (size_t)(m0 + row) * 128 + cg * 8;
            a0 = *reinterpret_cast<const float4*>(p);
            a1 = *reinterpret_cast<const float4*>(p + 4);
        }
        u16x8 u;
        u[0] = f2b(a0.x); u[1] = f2b(a0.y); u[2] = f2b(a0.z); u[3] = f2b(a0.w);
        u[4] = f2b(a1.x); u[5] = f2b(a1.y); u[6] = f2b(a1.z); u[7] = f2b(a1.w);
        const int off = row * 256 + ((cg * 16) ^ ((row & 7) << 4));
        *reinterpret_cast<u16x8*>((char*)Asw + off) = u;
    }
    __syncthreads();

    const int wv = t >> 6, lane = t & 63;
    const int mh = wv >> 2;          // row half (0/1)
    const int wn = wv & 3;           // 128-col slice
    const int l15 = lane & 15, lg = lane >> 4;
    const int nbb = wn * 8;

    f32x4 acc[4][8];
    #pragma unroll
    for (int mi = 0; mi < 4; ++mi)
        #pragma unroll
        for (int ni = 0; ni < 8; ++ni)
            acc[mi][ni] = (f32x4){0.f, 0.f, 0.f, 0.f};

    #pragma unroll
    for (int ks = 0; ks < 4; ++ks) {
        bf16x8 bfr[8];
        #pragma unroll
        for (int ni = 0; ni < 8; ++ni)
            bfr[ni] = *reinterpret_cast<const bf16x8*>(
                Bp + (size_t)(((nbb + ni) * 4 + ks) * 64 + lane) * 8);
        bf16x8 afr[4];
        #pragma unroll
        for (int mi = 0; mi < 4; ++mi) {
            const int row = mh * 64 + mi * 16 + l15;
            const int off = row * 256 + ((ks * 64 + lg * 16) ^ ((row & 7) << 4));
            afr[mi] = *reinterpret_cast<const bf16x8*>((const char*)Asw + off);
        }
        #pragma unroll
        for (int mi = 0; mi < 4; ++mi)
            #pragma unroll
            for (int ni = 0; ni < 8; ++ni)
                acc[mi][ni] = __builtin_amdgcn_mfma_f32_16x16x32_bf16(
                    afr[mi], bfr[ni], acc[mi][ni], 0, 0, 0);
    }

    // epilogue: D row = (lane>>4)*4 + r, col = lane&15  (m89-verified layout)
    #pragma unroll
    for (int ni = 0; ni < 8; ++ni) {
        const int col = wn * 128 + ni * 16 + l15;
        const bool isRes = (col >= 256);
        const float bv = isRes ? bres[col - 256] : 0.f;
        #pragma unroll
        for (int mi = 0; mi < 4; ++mi) {
            #pragma unroll
            for (int r = 0; r < 4; ++r) {
                const int row = m0 + mh * 64 + mi * 16 + lg * 4 + r;
                if (row >= Nrows) continue;
                const float v = acc[mi][ni][r];
                if (isRes) resid[(size_t)row * 256 + (col - 256)] = f2b(v + bv);
                else       pool [(size_t)row * 256 + col]         = f2b(v);
            }
        }
    }
}

// ---------------------------------------------------------------------------
// Per-pool head scores (bf16 pool)
// ---------------------------------------------------------------------------
__global__ __launch_bounds__(256)
void scores_k(const unsigned short* __restrict__ pool,
              const float* __restrict__ wvA, const float* __restrict__ wvB,
              float* __restrict__ elOut, float* __restrict__ erOut, int Nrows)
{
    const int lane = threadIdx.x & 63;
    const int n = blockIdx.x * 4 + (threadIdx.x >> 6);
    if (n >= Nrows) return;
    const int k = lane >> 3, d0 = (lane & 7) * 4;
    float4 f  = load4b(pool + (size_t)n * 256 + lane * 4);
    float4 wl = *reinterpret_cast<const float4*>(wvA + k * 64 + d0);
    float4 wr = *reinterpret_cast<const float4*>(wvB + k * 64 + 32 + d0);
    float pl = dot4(f, wl);
    float pr = dot4(f, wr);
    #pragma unroll
    for (int m = 1; m < 8; m <<= 1) {
        pl += __shfl_xor(pl, m, 64);
        pr += __shfl_xor(pr, m, 64);
    }
    if ((lane & 7) == 0) {
        elOut[(size_t)n * 8 + k] = pl;
        erOut[(size_t)n * 8 + k] = pr;
    }
}

// ---------------------------------------------------------------------------
// CSR build (batched over 4 relations via blockIdx.y)
// ---------------------------------------------------------------------------
struct EdgePtrs {
    const int* src[4];
    const int* dst[4];
    int E[4];
    int csrOff[4];
};

__global__ __launch_bounds__(256)
void hist_k(EdgePtrs ep, int* __restrict__ counts4, int N)
{
    const int r = blockIdx.y;
    const int e = blockIdx.x * 256 + threadIdx.x;
    if (e < ep.E[r]) atomicAdd(counts4 + (size_t)r * N + ep.dst[r][e], 1);
}

__global__ __launch_bounds__(256)
void blksum_k(const int* __restrict__ counts4, int* __restrict__ blksum4, int N)
{
    const int r = blockIdx.y;
    const int* c = counts4 + (size_t)r * N;
    const int base = blockIdx.x * 1024 + threadIdx.x;
    int s = 0;
    #pragma unroll
    for (int i = 0; i < 4; ++i) { int idx = base + i * 256; if (idx < N) s += c[idx]; }
    __shared__ int sd[256];
    sd[threadIdx.x] = s; __syncthreads();
    for (int off = 128; off > 0; off >>= 1) {
        if (threadIdx.x < off) sd[threadIdx.x] += sd[threadIdx.x + off];
        __syncthreads();
    }
    if (threadIdx.x == 0) blksum4[r * 1024 + blockIdx.x] = sd[0];
}

__global__ __launch_bounds__(1024)
void scanblk_k(int* __restrict__ blksum4, int nbx)
{
    const int r = blockIdx.x;
    const int t = threadIdx.x;
    __shared__ int sd[1024];
    int v = (t < nbx) ? blksum4[r * 1024 + t] : 0;
    sd[t] = v; __syncthreads();
    for (int off = 1; off < 1024; off <<= 1) {
        int u = (t >= off) ? sd[t - off] : 0;
        __syncthreads();
        sd[t] += u;
        __syncthreads();
    }
    if (t < nbx) blksum4[r * 1024 + t] = sd[t] - v;
}

__global__ __launch_bounds__(256)
void cursor_k(const int* __restrict__ counts4, const int* __restrict__ blkoff4,
              int* __restrict__ cursor4, int N)
{
    const int r = blockIdx.y;
    const int* c = counts4 + (size_t)r * N;
    int* cur = cursor4 + (size_t)r * N;
    const int t = threadIdx.x;
    const int base = blockIdx.x * 1024 + t * 4;
    const int c0 = (base + 0 < N) ? c[base + 0] : 0;
    const int c1 = (base + 1 < N) ? c[base + 1] : 0;
    const int c2 = (base + 2 < N) ? c[base + 2] : 0;
    const int c3 = (base + 3 < N) ? c[base + 3] : 0;
    const int tsum = c0 + c1 + c2 + c3;
    __shared__ int sd[256];
    sd[t] = tsum; __syncthreads();
    for (int off = 1; off < 256; off <<= 1) {
        int u = (t >= off) ? sd[t - off] : 0;
        __syncthreads();
        sd[t] += u;
        __syncthreads();
    }
    int excl = sd[t] - tsum + blkoff4[r * 1024 + blockIdx.x];
    if (base + 0 < N) cur[base + 0] = excl;
    if (base + 1 < N) cur[base + 1] = excl + c0;
    if (base + 2 < N) cur[base + 2] = excl + c0 + c1;
    if (base + 3 < N) cur[base + 3] = excl + c0 + c1 + c2;
}

__global__ __launch_bounds__(256)
void scatter_k(EdgePtrs ep, int* __restrict__ cursor4, int* __restrict__ csr_src, int N)
{
    const int r = blockIdx.y;
    const int e = blockIdx.x * 256 + threadIdx.x;
    if (e < ep.E[r]) {
        const int d = ep.dst[r][e];
        const int pos = atomicAdd(cursor4 + (size_t)r * N + d, 1);
        csr_src[ep.csrOff[r] + pos] = ep.src[r][e];
    }
}

// ---------------------------------------------------------------------------
// Fused edge-softmax + aggregation (bf16 fs, fp32 accum, bf16 agg out)
// ---------------------------------------------------------------------------
__global__ __launch_bounds__(256)
void aggr_k(const int* __restrict__ csr_src, const int* __restrict__ cursor,
            const int* __restrict__ counts,
            const float* __restrict__ el, const float* __restrict__ er,
            const unsigned short* __restrict__ fs, unsigned short* __restrict__ agg,
            int Nrows)
{
    const int lane = threadIdx.x & 63;
    const int n = blockIdx.x * 4 + (threadIdx.x >> 6);
    if (n >= Nrows) return;
    const int k = lane >> 3;
    const int deg = counts[n];
    const int end = cursor[n];
    const int start = end - deg;
    const float erk = er[(size_t)n * 8 + k];
    float s = 0.f;
    float4 acc = make_float4(0.f, 0.f, 0.f, 0.f);
    for (int j = start; j < end; ++j) {
        const int si = csr_src[j];
        const float ex = expf(lrelu(el[(size_t)si * 8 + k] + erk));
        s += ex;
        float4 f = load4b(fs + (size_t)si * 256 + lane * 4);
        acc.x = fmaf(f.x, ex, acc.x);
        acc.y = fmaf(f.y, ex, acc.y);
        acc.z = fmaf(f.z, ex, acc.z);
        acc.w = fmaf(f.w, ex, acc.w);
    }
    const float inv = (deg > 0) ? 1.f / s : 0.f;
    u16x4 o;
    o[0] = f2b(acc.x * inv); o[1] = f2b(acc.y * inv);
    o[2] = f2b(acc.z * inv); o[3] = f2b(acc.w * inv);
    *reinterpret_cast<u16x4*>(agg + (size_t)n * 256 + lane * 4) = o;
}

// ---------------------------------------------------------------------------
// Combine: gated residual + cross-relation softmax fusion; out_iu passthrough
// ---------------------------------------------------------------------------
__global__ __launch_bounds__(256)
void combine_k(const unsigned short* __restrict__ g0, const unsigned short* __restrict__ g1,
               const unsigned short* __restrict__ g2, const unsigned short* __restrict__ g3,
               const unsigned short* __restrict__ r0, const unsigned short* __restrict__ r1,
               const unsigned short* __restrict__ r2, const unsigned short* __restrict__ r3,
               const float* __restrict__ attn_ui, const float* __restrict__ attn_ii,
               const float* __restrict__ attn_iir,
               const float* __restrict__ a_user, const float* __restrict__ a_item,
               float* __restrict__ out, int Nrows)
{
    const int lane = threadIdx.x & 63;
    const int n = blockIdx.x * 4 + (threadIdx.x >> 6);
    if (n >= Nrows) return;
    const size_t o = (size_t)n * 256 + lane * 4;
    const float si = 1.f / (1.f + expf(-a_item[0])), osi = 1.f - si;
    const float su = 1.f / (1.f + expf(-a_user[0])), osu = 1.f - su;

    float4 G0 = load4b(g0 + o), G1 = load4b(g1 + o), G2 = load4b(g2 + o), G3 = load4b(g3 + o);
    float4 R0 = load4b(r0 + o), R1 = load4b(r1 + o), R2 = load4b(r2 + o), R3 = load4b(r3 + o);
    float4 f0, f1, f2, fiu;
    f0.x = si * fmaxf(G0.x, 0.f) + osi * R0.x;  f0.y = si * fmaxf(G0.y, 0.f) + osi * R0.y;
    f0.z = si * fmaxf(G0.z, 0.f) + osi * R0.z;  f0.w = si * fmaxf(G0.w, 0.f) + osi * R0.w;
    fiu.x = su * fmaxf(G1.x, 0.f) + osu * R1.x; fiu.y = su * fmaxf(G1.y, 0.f) + osu * R1.y;
    fiu.z = su * fmaxf(G1.z, 0.f) + osu * R1.z; fiu.w = su * fmaxf(G1.w, 0.f) + osu * R1.w;
    f1.x = si * fmaxf(G2.x, 0.f) + osi * R2.x;  f1.y = si * fmaxf(G2.y, 0.f) + osi * R2.y;
    f1.z = si * fmaxf(G2.z, 0.f) + osi * R2.z;  f1.w = si * fmaxf(G2.w, 0.f) + osi * R2.w;
    f2.x = si * fmaxf(G3.x, 0.f) + osi * R3.x;  f2.y = si * fmaxf(G3.y, 0.f) + osi * R3.y;
    f2.z = si * fmaxf(G3.z, 0.f) + osi * R3.z;  f2.w = si * fmaxf(G3.w, 0.f) + osi * R3.w;

    float4 w0 = *reinterpret_cast<const float4*>(attn_ui  + lane * 4);
    float4 w1 = *reinterpret_cast<const float4*>(attn_ii  + lane * 4);
    float4 w2 = *reinterpret_cast<const float4*>(attn_iir + lane * 4);

    float p[3][3];
    p[0][0] = dot4(w0, f0); p[0][1] = dot4(w0, f1); p[0][2] = dot4(w0, f2);
    p[1][0] = dot4(w1, f0); p[1][1] = dot4(w1, f1); p[1][2] = dot4(w1, f2);
    p[2][0] = dot4(w2, f0); p[2][1] = dot4(w2, f1); p[2][2] = dot4(w2, f2);
    #pragma unroll
    for (int x = 0; x < 3; ++x)
        #pragma unroll
        for (int r = 0; r < 3; ++r)
            #pragma unroll
            for (int m = 1; m < 8; m <<= 1)
                p[x][r] += __shfl_xor(p[x][r], m, 64);

    const size_t NK = (size_t)Nrows * 256;
    const size_t xoff[3] = {0, 2 * NK, 3 * NK};
    #pragma unroll
    for (int x = 0; x < 3; ++x) {
        float a0 = lrelu(p[x][0]), a1 = lrelu(p[x][1]), a2 = lrelu(p[x][2]);
        float mx = fmaxf(a0, fmaxf(a1, a2));
        float e0 = expf(a0 - mx), e1 = expf(a1 - mx), e2 = expf(a2 - mx);
        float inv = 1.f / (e0 + e1 + e2);
        e0 *= inv; e1 *= inv; e2 *= inv;
        float4 rr;
        rr.x = e0 * f0.x + e1 * f1.x + e2 * f2.x;
        rr.y = e0 * f0.y + e1 * f1.y + e2 * f2.y;
        rr.z = e0 * f0.z + e1 * f1.z + e2 * f2.z;
        rr.w = e0 * f0.w + e1 * f1.w + e2 * f2.w;
        *reinterpret_cast<float4*>(out + xoff[x] + o) = rr;
    }
    *reinterpret_cast<float4*>(out + NK + o) = fiu;
}

// ---------------------------------------------------------------------------
// Relation-level tiny matvecs
// ---------------------------------------------------------------------------
struct RelPtrs {
    const float* rf[4];
    const float* Wrel[4];
    const float* Wupd[4];
    const float* bupd[4];
};

__global__ __launch_bounds__(512)
void rel_k(RelPtrs P, float* __restrict__ wvec, float* __restrict__ ro)
{
    const int r = blockIdx.x;
    const int t = threadIdx.x;
    __shared__ float rfs[64];
    if (t < 64) rfs[t] = P.rf[r][t];
    __syncthreads();
    {
        const float* Wc = P.Wrel[r];
        float acc = 0.f;
        #pragma unroll 8
        for (int i = 0; i < 64; ++i) acc = fmaf(rfs[i], Wc[(size_t)i * 512 + t], acc);
        wvec[(size_t)r * 512 + t] = acc;
    }
    if (t < 256) {
        const float* Wc = P.Wupd[r];
        float acc = P.bupd[r][t];
        #pragma unroll 8
        for (int i = 0; i < 64; ++i) acc = fmaf(rfs[i], Wc[(size_t)i * 256 + t], acc);
        ro[(size_t)r * 256 + t] = acc;
    }
}

// ---------------------------------------------------------------------------
extern "C" void kernel_launch(void* const* d_in, const int* in_sizes, int n_in,
                              void* d_out, int out_size, void* d_ws, size_t ws_size,
                              hipStream_t stream)
{
    (void)n_in; (void)out_size; (void)ws_size;
    const float* feat_ui  = (const float*)d_in[0];
    const float* feat_iu  = (const float*)d_in[1];
    const float* feat_ii  = (const float*)d_in[2];
    const float* feat_iir = (const float*)d_in[3];
    const float* W_user   = (const float*)d_in[8];
    const float* W_item   = (const float*)d_in[9];
    const float* Wres_user = (const float*)d_in[18];
    const float* bres_user = (const float*)d_in[19];
    const float* Wres_item = (const float*)d_in[20];
    const float* bres_item = (const float*)d_in[21];
    const float* a_user = (const float*)d_in[22];
    const float* a_item = (const float*)d_in[23];
    const int N = in_sizes[0] / 128;
    const int Es[4] = {in_sizes[32], in_sizes[34], in_sizes[36], in_sizes[38]};
    int maxE = 0;
    for (int r = 0; r < 4; ++r) maxE = Es[r] > maxE ? Es[r] : maxE;

    const size_t NP = (size_t)N * 256;
    const size_t N8 = (size_t)N * 8;

    unsigned short* us = (unsigned short*)d_ws;
    unsigned short* pool[4];   // P0=fiu@Wu, P1=fui@Wi, P2=fiir@Wi, P3=fii@Wi
    unsigned short* resid[4];  // r_ui(from fui), r_iu(from fiu), r_ii(from fii), r_iir(from fiir)
    unsigned short* agg[4];
    for (int r = 0; r < 4; ++r) pool[r]  = us + (size_t)r * NP;
    for (int r = 0; r < 4; ++r) resid[r] = us + (size_t)(4 + r) * NP;
    for (int r = 0; r < 4; ++r) agg[r]   = us + (size_t)(8 + r) * NP;
    unsigned short* Bp_user = us + 12 * NP;           // [W_user | Wres_user] frags
    unsigned short* Bp_item = Bp_user + 65536;        // [W_item | Wres_item] frags
    float* fl = (float*)(Bp_item + 65536);
    float *el[4], *er[4];
    for (int r = 0; r < 4; ++r) { el[r] = fl + (size_t)(2 * r) * N8; er[r] = fl + (size_t)(2 * r + 1) * N8; }
    float* wvec = fl + 8 * N8;                        // 4 x 512
    int* counts4 = (int*)(wvec + 4 * 512);
    int* cursor4 = counts4 + 4 * (size_t)N;
    int* blksum4 = cursor4 + 4 * (size_t)N;
    int* csr_src = blksum4 + 4 * 1024;
    float* out = (float*)d_out;

    EdgePtrs ep;
    {
        int off = 0;
        const int si[4] = {32, 34, 36, 38};
        for (int r = 0; r < 4; ++r) {
            ep.src[r] = (const int*)d_in[si[r]];
            ep.dst[r] = (const int*)d_in[si[r] + 1];
            ep.E[r] = Es[r];
            ep.csrOff[r] = off;
            off += Es[r];
        }
    }

    (void)hipMemsetAsync(counts4, 0, 4 * (size_t)N * sizeof(int), stream);

    RelPtrs rp;
    rp.rf[0]   = (const float*)d_in[4];  rp.rf[1]   = (const float*)d_in[5];
    rp.rf[2]   = (const float*)d_in[6];  rp.rf[3]   = (const float*)d_in[7];
    rp.Wrel[0] = (const float*)d_in[10]; rp.Wrel[1] = (const float*)d_in[11];
    rp.Wrel[2] = (const float*)d_in[12]; rp.Wrel[3] = (const float*)d_in[13];
    rp.Wupd[0] = (const float*)d_in[24]; rp.Wupd[1] = (const float*)d_in[26];
    rp.Wupd[2] = (const float*)d_in[28]; rp.Wupd[3] = (const float*)d_in[30];
    rp.bupd[0] = (const float*)d_in[25]; rp.bupd[1] = (const float*)d_in[27];
    rp.bupd[2] = (const float*)d_in[29]; rp.bupd[3] = (const float*)d_in[31];
    rel_k<<<dim3(4), dim3(512), 0, stream>>>(rp, wvec, out + 4 * NP);

    // pack both weight pairs into MFMA fragment order (bf16)
    pack_b_k<<<32, 256, 0, stream>>>(W_user, Wres_user, Bp_user);
    pack_b_k<<<32, 256, 0, stream>>>(W_item, Wres_item, Bp_item);

    // CSR build
    const int geb = (maxE + 255) / 256;
    const int nbx = (N + 1023) / 1024;
    hist_k<<<dim3(geb, 4), 256, 0, stream>>>(ep, counts4, N);
    blksum_k<<<dim3(nbx, 4), 256, 0, stream>>>(counts4, blksum4, N);
    scanblk_k<<<dim3(4), 1024, 0, stream>>>(blksum4, nbx);
    cursor_k<<<dim3(nbx, 4), 256, 0, stream>>>(counts4, blksum4, cursor4, N);
    scatter_k<<<dim3(geb, 4), 256, 0, stream>>>(ep, cursor4, csr_src, N);

    // fused pool+residual GEMMs (one per feat matrix)
    const int gb = (N + 127) / 128;
    mfma_gemm_k<<<gb, 512, 0, stream>>>(feat_iu,  Bp_user, bres_user, pool[0], resid[1], N);
    mfma_gemm_k<<<gb, 512, 0, stream>>>(feat_ui,  Bp_item, bres_item, pool[1], resid[0], N);
    mfma_gemm_k<<<gb, 512, 0, stream>>>(feat_iir, Bp_item, bres_item, pool[2], resid[3], N);
    mfma_gemm_k<<<gb, 512, 0, stream>>>(feat_ii,  Bp_item, bres_item, pool[3], resid[2], N);

    // head scores
    const int nb4 = (N + 3) / 4;
    scores_k<<<nb4, 256, 0, stream>>>(pool[0], wvec + 0 * 512, wvec + 1 * 512, el[0], er[1], N);
    scores_k<<<nb4, 256, 0, stream>>>(pool[1], wvec + 1 * 512, wvec + 0 * 512, el[1], er[0], N);
    scores_k<<<nb4, 256, 0, stream>>>(pool[2], wvec + 2 * 512, wvec + 3 * 512, el[2], er[3], N);
    scores_k<<<nb4, 256, 0, stream>>>(pool[3], wvec + 3 * 512, wvec + 2 * 512, el[3], er[2], N);

    // fused softmax + aggregation
    for (int r = 0; r < 4; ++r)
        aggr_k<<<nb4, 256, 0, stream>>>(csr_src + ep.csrOff[r],
                                        cursor4 + (size_t)r * N,
                                        counts4 + (size_t)r * N,
                                        el[r], er[r], pool[r], agg[r], N);

    // gated residual + cross-relation fusion + outputs
    combine_k<<<nb4, 256, 0, stream>>>(agg[0], agg[1], agg[2], agg[3],
                                       resid[0], resid[1], resid[2], resid[3],
                                       (const float*)d_in[14], (const float*)d_in[16],
                                       (const float*)d_in[17],
                                       a_user, a_item, out, N);
}

// Round 5
// 753.361 us; speedup vs baseline: 7.4582x; 1.4520x over previous
//
#include <hip/hip_runtime.h>
#include <hip/hip_bf16.h>
#include <math.h>

#define NEG_SLOPE 0.2f

using bf16x8 = __attribute__((ext_vector_type(8))) short;
using f32x4  = __attribute__((ext_vector_type(4))) float;
using u16x8  = __attribute__((ext_vector_type(8))) unsigned short;
using u16x4  = __attribute__((ext_vector_type(4))) unsigned short;

__device__ __forceinline__ float lrelu(float x) { return x > 0.f ? x : NEG_SLOPE * x; }
__device__ __forceinline__ float dot4(float4 a, float4 b) {
    return a.x * b.x + a.y * b.y + a.z * b.z + a.w * b.w;
}
__device__ __forceinline__ unsigned short f2b(float x) {
    union { float f; unsigned u; } v; v.f = x;
    unsigned r = v.u + 0x7fff + ((v.u >> 16) & 1);
    return (unsigned short)(r >> 16);
}
__device__ __forceinline__ float b2f(unsigned short b) {
    union { unsigned u; float f; } v; v.u = ((unsigned)b) << 16;
    return v.f;
}
__device__ __forceinline__ float4 load4b(const unsigned short* p) {
    u16x4 u = *reinterpret_cast<const u16x4*>(p);
    return make_float4(b2f(u[0]), b2f(u[1]), b2f(u[2]), b2f(u[3]));
}

// ---------------------------------------------------------------------------
// Pack Wcat = [W1 | W2] (each 128x256 fp32, k-major) into MFMA B-fragment
// linear order, bf16. Batched: blockIdx.y selects the weight pair.
// ---------------------------------------------------------------------------
struct PackArgs {
    const float* W1[2];
    const float* W2[2];
    unsigned short* Bp[2];
};

__global__ __launch_bounds__(256)
void pack_b_k(PackArgs pa)
{
    const int p = blockIdx.y;
    const int gid = blockIdx.x * 256 + threadIdx.x;  // 0..8191
    const int lane = gid & 63;
    const int grp = gid >> 6;          // 0..127
    const int ks = grp & 3;
    const int nb = grp >> 2;           // 0..31
    const int n = nb * 16 + (lane & 15);
    const int k0 = ks * 32 + (lane >> 4) * 8;
    const float* Wsrc = (n < 256) ? (pa.W1[p] + n) : (pa.W2[p] + (n - 256));
    u16x8 u;
    #pragma unroll
    for (int e = 0; e < 8; ++e) u[e] = f2b(Wsrc[(size_t)(k0 + e) * 256]);
    *reinterpret_cast<u16x8*>(pa.Bp[p] + (size_t)gid * 8) = u;
}

// ---------------------------------------------------------------------------
// MFMA GEMM, batched over 4 (A, W, outputs) tuples via blockIdx.y.
// A[N x 128] fp32 @ Wcat[128 x 512] bf16-frags -> pool (cols 0-255, bf16),
// resid (cols 256-511, +bres, bf16).
// Epilogue: LDS bounce -> fully-coalesced u16x8 stores.
// ---------------------------------------------------------------------------
struct GemmArgs {
    const float* A[4];
    const unsigned short* Bp[4];
    const float* bres[4];
    unsigned short* pool[4];
    unsigned short* resid[4];
};

__global__ __launch_bounds__(512)
void mfma_gemm_k(GemmArgs ga, int Nrows)
{
    __shared__ __align__(16) char smem[65536];
    unsigned short* Asw = (unsigned short*)smem;
    const int rsel = blockIdx.y;
    const float* __restrict__ A = ga.A[rsel];
    const unsigned short* __restrict__ Bp = ga.Bp[rsel];
    const float* __restrict__ bres = ga.bres[rsel];
    const int t = threadIdx.x;
    const int m0 = blockIdx.x * 128;

    // stage A: 128 rows x 128 k, fp32 -> bf16, XOR-swizzled (first 32 KB)
    #pragma unroll
    for (int i = 0; i < 4; ++i) {
        const int idx = i * 512 + t;        // 0..2047
        const int row = idx >> 4;           // 0..127
        const int cg  = idx & 15;           // 16B chunk (8 bf16)
        float4 a0 = make_float4(0.f, 0.f, 0.f, 0.f), a1 = a0;
        if (m0 + row < Nrows) {
            const float* p = A + (size_t)(m0 + row) * 128 + cg * 8;
            a0 = *reinterpret_cast<const float4*>(p);
            a1 = *reinterpret_cast<const float4*>(p + 4);
        }
        u16x8 u;
        u[0] = f2b(a0.x); u[1] = f2b(a0.y); u[2] = f2b(a0.z); u[3] = f2b(a0.w);
        u[4] = f2b(a1.x); u[5] = f2b(a1.y); u[6] = f2b(a1.z); u[7] = f2b(a1.w);
        const int off = row * 256 + ((cg * 16) ^ ((row & 7) << 4));
        *reinterpret_cast<u16x8*>((char*)Asw + off) = u;
    }
    __syncthreads();

    const int wv = t >> 6, lane = t & 63;
    const int mh = wv >> 2;          // row half (0/1)
    const int wn = wv & 3;           // 128-col slice
    const int l15 = lane & 15, lg = lane >> 4;
    const int nbb = wn * 8;

    f32x4 acc[4][8];
    #pragma unroll
    for (int mi = 0; mi < 4; ++mi)
        #pragma unroll
        for (int ni = 0; ni < 8; ++ni)
            acc[mi][ni] = (f32x4){0.f, 0.f, 0.f, 0.f};

    #pragma unroll
    for (int ks = 0; ks < 4; ++ks) {
        bf16x8 bfr[8];
        #pragma unroll
        for (int ni = 0; ni < 8; ++ni)
            bfr[ni] = *reinterpret_cast<const bf16x8*>(
                Bp + (size_t)(((nbb + ni) * 4 + ks) * 64 + lane) * 8);
        bf16x8 afr[4];
        #pragma unroll
        for (int mi = 0; mi < 4; ++mi) {
            const int row = mh * 64 + mi * 16 + l15;
            const int off = row * 256 + ((ks * 64 + lg * 16) ^ ((row & 7) << 4));
            afr[mi] = *reinterpret_cast<const bf16x8*>((const char*)Asw + off);
        }
        #pragma unroll
        for (int mi = 0; mi < 4; ++mi)
            #pragma unroll
            for (int ni = 0; ni < 8; ++ni)
                acc[mi][ni] = __builtin_amdgcn_mfma_f32_16x16x32_bf16(
                    afr[mi], bfr[ni], acc[mi][ni], 0, 0, 0);
    }
    __syncthreads();

    // epilogue: 2 passes (pool = wn 0/1, resid = wn 2/3) through 64 KB LDS
    #pragma unroll
    for (int pass = 0; pass < 2; ++pass) {
        if ((wn >> 1) == pass) {
            const int colbase = (wn & 1) * 128;
            #pragma unroll
            for (int ni = 0; ni < 8; ++ni) {
                const int col = colbase + ni * 16 + l15;
                const float bv = pass ? bres[col] : 0.f;
                #pragma unroll
                for (int mi = 0; mi < 4; ++mi) {
                    #pragma unroll
                    for (int r = 0; r < 4; ++r) {
                        const int row = mh * 64 + mi * 16 + lg * 4 + r;
                        const int byte = row * 512 + ((col * 2) ^ ((row & 7) << 4));
                        *reinterpret_cast<unsigned short*>(smem + byte) =
                            f2b(acc[mi][ni][r] + bv);
                    }
                }
            }
        }
        __syncthreads();
        unsigned short* dst = pass ? ga.resid[rsel] : ga.pool[rsel];
        #pragma unroll
        for (int i = 0; i < 8; ++i) {
            const int idx = i * 512 + t;     // 0..4095 16B chunks
            const int row = idx >> 5;        // 32 chunks per 512B row
            const int c16 = idx & 31;
            const int byte = row * 512 + ((c16 * 16) ^ ((row & 7) << 4));
            u16x8 v = *reinterpret_cast<const u16x8*>(smem + byte);
            if (m0 + row < Nrows)
                *reinterpret_cast<u16x8*>(dst + (size_t)(m0 + row) * 256 + c16 * 8) = v;
        }
        __syncthreads();
    }
}

// ---------------------------------------------------------------------------
// Per-pool head scores, batched over 4 pools via blockIdx.y
// ---------------------------------------------------------------------------
struct ScArgs {
    const unsigned short* pool[4];
    const float* wvA[4];
    const float* wvB[4];
    float* elOut[4];
    float* erOut[4];
};

__global__ __launch_bounds__(256)
void scores_k(ScArgs sa, int Nrows)
{
    const int r = blockIdx.y;
    const int lane = threadIdx.x & 63;
    const int n = blockIdx.x * 4 + (threadIdx.x >> 6);
    if (n >= Nrows) return;
    const int k = lane >> 3, d0 = (lane & 7) * 4;
    float4 f  = load4b(sa.pool[r] + (size_t)n * 256 + lane * 4);
    float4 wl = *reinterpret_cast<const float4*>(sa.wvA[r] + k * 64 + d0);
    float4 wr = *reinterpret_cast<const float4*>(sa.wvB[r] + k * 64 + 32 + d0);
    float pl = dot4(f, wl);
    float pr = dot4(f, wr);
    #pragma unroll
    for (int m = 1; m < 8; m <<= 1) {
        pl += __shfl_xor(pl, m, 64);
        pr += __shfl_xor(pr, m, 64);
    }
    if ((lane & 7) == 0) {
        sa.elOut[r][(size_t)n * 8 + k] = pl;
        sa.erOut[r][(size_t)n * 8 + k] = pr;
    }
}

// ---------------------------------------------------------------------------
// CSR build (batched over 4 relations via blockIdx.y)
// ---------------------------------------------------------------------------
struct EdgePtrs {
    const int* src[4];
    const int* dst[4];
    int E[4];
    int csrOff[4];
};

__global__ __launch_bounds__(256)
void hist_k(EdgePtrs ep, int* __restrict__ counts4, int N)
{
    const int r = blockIdx.y;
    const int e = blockIdx.x * 256 + threadIdx.x;
    if (e < ep.E[r]) atomicAdd(counts4 + (size_t)r * N + ep.dst[r][e], 1);
}

__global__ __launch_bounds__(256)
void blksum_k(const int* __restrict__ counts4, int* __restrict__ blksum4, int N)
{
    const int r = blockIdx.y;
    const int* c = counts4 + (size_t)r * N;
    const int base = blockIdx.x * 1024 + threadIdx.x;
    int s = 0;
    #pragma unroll
    for (int i = 0; i < 4; ++i) { int idx = base + i * 256; if (idx < N) s += c[idx]; }
    __shared__ int sd[256];
    sd[threadIdx.x] = s; __syncthreads();
    for (int off = 128; off > 0; off >>= 1) {
        if (threadIdx.x < off) sd[threadIdx.x] += sd[threadIdx.x + off];
        __syncthreads();
    }
    if (threadIdx.x == 0) blksum4[r * 1024 + blockIdx.x] = sd[0];
}

__global__ __launch_bounds__(1024)
void scanblk_k(int* __restrict__ blksum4, int nbx)
{
    const int r = blockIdx.x;
    const int t = threadIdx.x;
    __shared__ int sd[1024];
    int v = (t < nbx) ? blksum4[r * 1024 + t] : 0;
    sd[t] = v; __syncthreads();
    for (int off = 1; off < 1024; off <<= 1) {
        int u = (t >= off) ? sd[t - off] : 0;
        __syncthreads();
        sd[t] += u;
        __syncthreads();
    }
    if (t < nbx) blksum4[r * 1024 + t] = sd[t] - v;
}

__global__ __launch_bounds__(256)
void cursor_k(const int* __restrict__ counts4, const int* __restrict__ blkoff4,
              int* __restrict__ cursor4, int N)
{
    const int r = blockIdx.y;
    const int* c = counts4 + (size_t)r * N;
    int* cur = cursor4 + (size_t)r * N;
    const int t = threadIdx.x;
    const int base = blockIdx.x * 1024 + t * 4;
    const int c0 = (base + 0 < N) ? c[base + 0] : 0;
    const int c1 = (base + 1 < N) ? c[base + 1] : 0;
    const int c2 = (base + 2 < N) ? c[base + 2] : 0;
    const int c3 = (base + 3 < N) ? c[base + 3] : 0;
    const int tsum = c0 + c1 + c2 + c3;
    __shared__ int sd[256];
    sd[t] = tsum; __syncthreads();
    for (int off = 1; off < 256; off <<= 1) {
        int u = (t >= off) ? sd[t - off] : 0;
        __syncthreads();
        sd[t] += u;
        __syncthreads();
    }
    int excl = sd[t] - tsum + blkoff4[r * 1024 + blockIdx.x];
    if (base + 0 < N) cur[base + 0] = excl;
    if (base + 1 < N) cur[base + 1] = excl + c0;
    if (base + 2 < N) cur[base + 2] = excl + c0 + c1;
    if (base + 3 < N) cur[base + 3] = excl + c0 + c1 + c2;
}

__global__ __launch_bounds__(256)
void scatter_k(EdgePtrs ep, int* __restrict__ cursor4, int* __restrict__ csr_src, int N)
{
    const int r = blockIdx.y;
    const int e = blockIdx.x * 256 + threadIdx.x;
    if (e < ep.E[r]) {
        const int d = ep.dst[r][e];
        const int pos = atomicAdd(cursor4 + (size_t)r * N + d, 1);
        csr_src[ep.csrOff[r] + pos] = ep.src[r][e];
    }
}

// ---------------------------------------------------------------------------
// Fused per-node kernel: for each node, aggregate all 4 relations (edge
// softmax + weighted gather, fp32 accum), apply gated residual, then the
// cross-relation softmax fusion. One wave per node. Writes all outputs.
// ---------------------------------------------------------------------------
struct NodeArgs {
    const int* csr[4];
    const int* cursor[4];
    const int* counts[4];
    const float* el[4];
    const float* er[4];
    const unsigned short* pool[4];
    const unsigned short* resid[4];
};

__global__ __launch_bounds__(256)
void node_k(NodeArgs na,
            const float* __restrict__ attn_ui, const float* __restrict__ attn_ii,
            const float* __restrict__ attn_iir,
            const float* __restrict__ a_user, const float* __restrict__ a_item,
            float* __restrict__ out, int Nrows)
{
    const int lane = threadIdx.x & 63;
    const int n = blockIdx.x * 4 + (threadIdx.x >> 6);
    if (n >= Nrows) return;
    const int k = lane >> 3;

    float4 g[4];
    #pragma unroll
    for (int r = 0; r < 4; ++r) {
        const int deg = na.counts[r][n];
        const int end = na.cursor[r][n];
        const int start = end - deg;
        const float erk = na.er[r][(size_t)n * 8 + k];
        const int* __restrict__ csr = na.csr[r];
        const float* __restrict__ elr = na.el[r];
        const unsigned short* __restrict__ fs = na.pool[r];
        float s = 0.f;
        float4 acc = make_float4(0.f, 0.f, 0.f, 0.f);
        for (int j = start; j < end; ++j) {
            const int si = csr[j];
            const float ex = expf(lrelu(elr[(size_t)si * 8 + k] + erk));
            s += ex;
            float4 f = load4b(fs + (size_t)si * 256 + lane * 4);
            acc.x = fmaf(f.x, ex, acc.x);
            acc.y = fmaf(f.y, ex, acc.y);
            acc.z = fmaf(f.z, ex, acc.z);
            acc.w = fmaf(f.w, ex, acc.w);
        }
        const float inv = (deg > 0) ? 1.f / s : 0.f;
        g[r] = make_float4(acc.x * inv, acc.y * inv, acc.z * inv, acc.w * inv);
    }

    const size_t o = (size_t)n * 256 + lane * 4;
    const float si = 1.f / (1.f + expf(-a_item[0])), osi = 1.f - si;
    const float su = 1.f / (1.f + expf(-a_user[0])), osu = 1.f - su;
    float4 R0 = load4b(na.resid[0] + o), R1 = load4b(na.resid[1] + o);
    float4 R2 = load4b(na.resid[2] + o), R3 = load4b(na.resid[3] + o);

    float4 f0, f1, f2, fiu;
    f0.x = si * fmaxf(g[0].x, 0.f) + osi * R0.x;  f0.y = si * fmaxf(g[0].y, 0.f) + osi * R0.y;
    f0.z = si * fmaxf(g[0].z, 0.f) + osi * R0.z;  f0.w = si * fmaxf(g[0].w, 0.f) + osi * R0.w;
    fiu.x = su * fmaxf(g[1].x, 0.f) + osu * R1.x; fiu.y = su * fmaxf(g[1].y, 0.f) + osu * R1.y;
    fiu.z = su * fmaxf(g[1].z, 0.f) + osu * R1.z; fiu.w = su * fmaxf(g[1].w, 0.f) + osu * R1.w;
    f1.x = si * fmaxf(g[2].x, 0.f) + osi * R2.x;  f1.y = si * fmaxf(g[2].y, 0.f) + osi * R2.y;
    f1.z = si * fmaxf(g[2].z, 0.f) + osi * R2.z;  f1.w = si * fmaxf(g[2].w, 0.f) + osi * R2.w;
    f2.x = si * fmaxf(g[3].x, 0.f) + osi * R3.x;  f2.y = si * fmaxf(g[3].y, 0.f) + osi * R3.y;
    f2.z = si * fmaxf(g[3].z, 0.f) + osi * R3.z;  f2.w = si * fmaxf(g[3].w, 0.f) + osi * R3.w;

    float4 w0 = *reinterpret_cast<const float4*>(attn_ui  + lane * 4);
    float4 w1 = *reinterpret_cast<const float4*>(attn_ii  + lane * 4);
    float4 w2 = *reinterpret_cast<const float4*>(attn_iir + lane * 4);

    float p[3][3];
    p[0][0] = dot4(w0, f0); p[0][1] = dot4(w0, f1); p[0][2] = dot4(w0, f2);
    p[1][0] = dot4(w1, f0); p[1][1] = dot4(w1, f1); p[1][2] = dot4(w1, f2);
    p[2][0] = dot4(w2, f0); p[2][1] = dot4(w2, f1); p[2][2] = dot4(w2, f2);
    #pragma unroll
    for (int x = 0; x < 3; ++x)
        #pragma unroll
        for (int r = 0; r < 3; ++r)
            #pragma unroll
            for (int m = 1; m < 8; m <<= 1)
                p[x][r] += __shfl_xor(p[x][r], m, 64);

    const size_t NK = (size_t)Nrows * 256;
    const size_t xoff[3] = {0, 2 * NK, 3 * NK};
    #pragma unroll
    for (int x = 0; x < 3; ++x) {
        float a0 = lrelu(p[x][0]), a1 = lrelu(p[x][1]), a2 = lrelu(p[x][2]);
        float mx = fmaxf(a0, fmaxf(a1, a2));
        float e0 = expf(a0 - mx), e1 = expf(a1 - mx), e2 = expf(a2 - mx);
        float inv = 1.f / (e0 + e1 + e2);
        e0 *= inv; e1 *= inv; e2 *= inv;
        float4 rr;
        rr.x = e0 * f0.x + e1 * f1.x + e2 * f2.x;
        rr.y = e0 * f0.y + e1 * f1.y + e2 * f2.y;
        rr.z = e0 * f0.z + e1 * f1.z + e2 * f2.z;
        rr.w = e0 * f0.w + e1 * f1.w + e2 * f2.w;
        *reinterpret_cast<float4*>(out + xoff[x] + o) = rr;
    }
    *reinterpret_cast<float4*>(out + NK + o) = fiu;
}

// ---------------------------------------------------------------------------
// Relation-level tiny matvecs
// ---------------------------------------------------------------------------
struct RelPtrs {
    const float* rf[4];
    const float* Wrel[4];
    const float* Wupd[4];
    const float* bupd[4];
};

__global__ __launch_bounds__(512)
void rel_k(RelPtrs P, float* __restrict__ wvec, float* __restrict__ ro)
{
    const int r = blockIdx.x;
    const int t = threadIdx.x;
    __shared__ float rfs[64];
    if (t < 64) rfs[t] = P.rf[r][t];
    __syncthreads();
    {
        const float* Wc = P.Wrel[r];
        float acc = 0.f;
        #pragma unroll 8
        for (int i = 0; i < 64; ++i) acc = fmaf(rfs[i], Wc[(size_t)i * 512 + t], acc);
        wvec[(size_t)r * 512 + t] = acc;
    }
    if (t < 256) {
        const float* Wc = P.Wupd[r];
        float acc = P.bupd[r][t];
        #pragma unroll 8
        for (int i = 0; i < 64; ++i) acc = fmaf(rfs[i], Wc[(size_t)i * 256 + t], acc);
        ro[(size_t)r * 256 + t] = acc;
    }
}

// ---------------------------------------------------------------------------
extern "C" void kernel_launch(void* const* d_in, const int* in_sizes, int n_in,
                              void* d_out, int out_size, void* d_ws, size_t ws_size,
                              hipStream_t stream)
{
    (void)n_in; (void)out_size; (void)ws_size;
    const float* feat_ui  = (const float*)d_in[0];
    const float* feat_iu  = (const float*)d_in[1];
    const float* feat_ii  = (const float*)d_in[2];
    const float* feat_iir = (const float*)d_in[3];
    const float* W_user   = (const float*)d_in[8];
    const float* W_item   = (const float*)d_in[9];
    const float* Wres_user = (const float*)d_in[18];
    const float* bres_user = (const float*)d_in[19];
    const float* Wres_item = (const float*)d_in[20];
    const float* bres_item = (const float*)d_in[21];
    const float* a_user = (const float*)d_in[22];
    const float* a_item = (const float*)d_in[23];
    const int N = in_sizes[0] / 128;
    const int Es[4] = {in_sizes[32], in_sizes[34], in_sizes[36], in_sizes[38]};
    int maxE = 0;
    for (int r = 0; r < 4; ++r) maxE = Es[r] > maxE ? Es[r] : maxE;

    const size_t NP = (size_t)N * 256;
    const size_t N8 = (size_t)N * 8;

    unsigned short* us = (unsigned short*)d_ws;
    unsigned short* pool[4];   // P0=fiu@Wu, P1=fui@Wi, P2=fiir@Wi, P3=fii@Wi
    unsigned short* resid[4];  // indexed by relation: 0:h_ui 1:h_iu 2:h_ii 3:h_iir
    for (int r = 0; r < 4; ++r) pool[r]  = us + (size_t)r * NP;
    for (int r = 0; r < 4; ++r) resid[r] = us + (size_t)(4 + r) * NP;
    unsigned short* Bp_user = us + 8 * NP;            // [W_user | Wres_user] frags
    unsigned short* Bp_item = Bp_user + 65536;        // [W_item | Wres_item] frags
    float* fl = (float*)(Bp_item + 65536);
    float *el[4], *er[4];
    for (int r = 0; r < 4; ++r) { el[r] = fl + (size_t)(2 * r) * N8; er[r] = fl + (size_t)(2 * r + 1) * N8; }
    float* wvec = fl + 8 * N8;                        // 4 x 512
    int* counts4 = (int*)(wvec + 4 * 512);
    int* cursor4 = counts4 + 4 * (size_t)N;
    int* blksum4 = cursor4 + 4 * (size_t)N;
    int* csr_src = blksum4 + 4 * 1024;
    float* out = (float*)d_out;

    EdgePtrs ep;
    {
        int off = 0;
        const int si[4] = {32, 34, 36, 38};
        for (int r = 0; r < 4; ++r) {
            ep.src[r] = (const int*)d_in[si[r]];
            ep.dst[r] = (const int*)d_in[si[r] + 1];
            ep.E[r] = Es[r];
            ep.csrOff[r] = off;
            off += Es[r];
        }
    }

    (void)hipMemsetAsync(counts4, 0, 4 * (size_t)N * sizeof(int), stream);

    RelPtrs rp;
    rp.rf[0]   = (const float*)d_in[4];  rp.rf[1]   = (const float*)d_in[5];
    rp.rf[2]   = (const float*)d_in[6];  rp.rf[3]   = (const float*)d_in[7];
    rp.Wrel[0] = (const float*)d_in[10]; rp.Wrel[1] = (const float*)d_in[11];
    rp.Wrel[2] = (const float*)d_in[12]; rp.Wrel[3] = (const float*)d_in[13];
    rp.Wupd[0] = (const float*)d_in[24]; rp.Wupd[1] = (const float*)d_in[26];
    rp.Wupd[2] = (const float*)d_in[28]; rp.Wupd[3] = (const float*)d_in[30];
    rp.bupd[0] = (const float*)d_in[25]; rp.bupd[1] = (const float*)d_in[27];
    rp.bupd[2] = (const float*)d_in[29]; rp.bupd[3] = (const float*)d_in[31];
    rel_k<<<dim3(4), dim3(512), 0, stream>>>(rp, wvec, out + 4 * NP);

    PackArgs pa;
    pa.W1[0] = W_user; pa.W2[0] = Wres_user; pa.Bp[0] = Bp_user;
    pa.W1[1] = W_item; pa.W2[1] = Wres_item; pa.Bp[1] = Bp_item;
    pack_b_k<<<dim3(32, 2), 256, 0, stream>>>(pa);

    // CSR build
    const int geb = (maxE + 255) / 256;
    const int nbx = (N + 1023) / 1024;
    hist_k<<<dim3(geb, 4), 256, 0, stream>>>(ep, counts4, N);
    blksum_k<<<dim3(nbx, 4), 256, 0, stream>>>(counts4, blksum4, N);
    scanblk_k<<<dim3(4), 1024, 0, stream>>>(blksum4, nbx);
    cursor_k<<<dim3(nbx, 4), 256, 0, stream>>>(counts4, blksum4, cursor4, N);
    scatter_k<<<dim3(geb, 4), 256, 0, stream>>>(ep, cursor4, csr_src, N);

    // fused pool+residual GEMMs, all 4 in one dispatch
    GemmArgs ga;
    ga.A[0] = feat_iu;  ga.Bp[0] = Bp_user; ga.bres[0] = bres_user; ga.pool[0] = pool[0]; ga.resid[0] = resid[1];
    ga.A[1] = feat_ui;  ga.Bp[1] = Bp_item; ga.bres[1] = bres_item; ga.pool[1] = pool[1]; ga.resid[1] = resid[0];
    ga.A[2] = feat_iir; ga.Bp[2] = Bp_item; ga.bres[2] = bres_item; ga.pool[2] = pool[2]; ga.resid[2] = resid[3];
    ga.A[3] = feat_ii;  ga.Bp[3] = Bp_item; ga.bres[3] = bres_item; ga.pool[3] = pool[3]; ga.resid[3] = resid[2];
    const int gb = (N + 127) / 128;
    mfma_gemm_k<<<dim3(gb, 4), 512, 0, stream>>>(ga, N);

    // head scores, all 4 pools in one dispatch
    // pool r pairs: wvA = wvec[r] (el[r]); wvB = wvec[pair], erOut = er[pair]
    const int pair[4] = {1, 0, 3, 2};
    ScArgs sa;
    for (int r = 0; r < 4; ++r) {
        sa.pool[r]  = pool[r];
        sa.wvA[r]   = wvec + (size_t)r * 512;
        sa.wvB[r]   = wvec + (size_t)pair[r] * 512;
        sa.elOut[r] = el[r];
        sa.erOut[r] = er[pair[r]];
    }
    const int nb4 = (N + 3) / 4;
    scores_k<<<dim3(nb4, 4), 256, 0, stream>>>(sa, N);

    // fused aggregation + gated residual + cross-relation fusion
    NodeArgs na;
    for (int r = 0; r < 4; ++r) {
        na.csr[r]    = csr_src + ep.csrOff[r];
        na.cursor[r] = cursor4 + (size_t)r * N;
        na.counts[r] = counts4 + (size_t)r * N;
        na.el[r]     = el[r];
        na.er[r]     = er[r];
        na.pool[r]   = pool[r];
        na.resid[r]  = resid[r];
    }
    node_k<<<nb4, 256, 0, stream>>>(na,
                                    (const float*)d_in[14], (const float*)d_in[16],
                                    (const float*)d_in[17],
                                    a_user, a_item, out, N);
}